// Round 3
// baseline (3297.916 us; speedup 1.0000x reference)
//
#include <hip/hip_runtime.h>
#include <hip/hip_bf16.h>

#define BATCH 2048
#define LSIG 2048
#define TSTEPS 512
#define CH 32            // LSTM steps per chunk
#define NCHUNK (TSTEPS / CH)

__device__ __forceinline__ float sigf(float x) {
    return __fdividef(1.f, 1.f + __expf(-x));
}
__device__ __forceinline__ float tanhfast(float x) {
    return 1.f - __fdividef(2.f, __expf(2.f * x) + 1.f);
}

// One 64-lane wave per (sample, branch): conv1(1->16,k3,p1) + relu + maxpool2
// -> conv2(16->32,k3,p1) + relu + maxpool2 -> LSTM(32->32, T=512) -> h_n[32]
// Register budget: ~128 LSTM weights + 48 conv2 weights per lane is the
// irreducible resident set -> launch_bounds(64,1) so the allocator does NOT
// cap at 128 and spill (round-2: 1.04GB FETCH / 258MB WRITE of scratch).
__global__ __launch_bounds__(64, 1) void branch_kernel(
    const float* __restrict__ x0, const float* __restrict__ x1,
    const float* __restrict__ x2, const float* __restrict__ x3,
    const float* __restrict__ c1w, const float* __restrict__ c1b,
    const float* __restrict__ c2w, const float* __restrict__ c2b,
    const float* __restrict__ wih, const float* __restrict__ whh,
    const float* __restrict__ bih, const float* __restrict__ bhh,
    float* __restrict__ feats)
{
    const int s    = blockIdx.x;
    const int br   = blockIdx.y;
    const int lane = threadIdx.x;
    const float* xg = (br == 0) ? x0 : (br == 1) ? x1 : (br == 2) ? x2 : x3;

    __shared__ float xs_c[136];             // per-chunk x window (zero-padded)
    __shared__ float p1buf[2 * CH + 2][16]; // pooled1 window for one chunk
    __shared__ float seqb[CH][32];          // LSTM inputs for one chunk
    __shared__ float hbuf[32];              // hidden state broadcast

    // ---- per-lane weights in registers ----
    const int ci1 = lane & 15;                  // conv1 out-channel for phase A
    const float w10 = c1w[br * 48 + ci1 * 3 + 0];
    const float w11 = c1w[br * 48 + ci1 * 3 + 1];
    const float w12 = c1w[br * 48 + ci1 * 3 + 2];
    const float b1v = c1b[br * 16 + ci1];

    const int co = lane & 31;                   // conv2 out-channel for phase B
    float w2r[48];
    {
        const float4* p = (const float4*)(c2w + br * 32 * 48 + co * 48);
        #pragma unroll
        for (int i = 0; i < 12; ++i) ((float4*)w2r)[i] = p[i];
    }
    const float b2v = c2b[br * 32 + co];

    // LSTM: lane j owns gate rows j and j+64 (torch order i,f,g,o)
    float wi0[32], wi1[32], wh0[32], wh1[32];
    {
        const float4* pi0 = (const float4*)(wih + (size_t)(br * 128 + lane) * 32);
        const float4* pi1 = (const float4*)(wih + (size_t)(br * 128 + lane + 64) * 32);
        const float4* ph0 = (const float4*)(whh + (size_t)(br * 128 + lane) * 32);
        const float4* ph1 = (const float4*)(whh + (size_t)(br * 128 + lane + 64) * 32);
        #pragma unroll
        for (int i = 0; i < 8; ++i) {
            ((float4*)wi0)[i] = pi0[i];
            ((float4*)wi1)[i] = pi1[i];
            ((float4*)wh0)[i] = ph0[i];
            ((float4*)wh1)[i] = ph1[i];
        }
    }
    const float bs0 = bih[br * 128 + lane]      + bhh[br * 128 + lane];
    const float bs1 = bih[br * 128 + lane + 64] + bhh[br * 128 + lane + 64];

    if (lane < 32) hbuf[lane] = 0.f;
    float c_state = 0.f;
    __syncthreads();

    const int tl_b = lane >> 5;   // phase-B row split

    for (int chk = 0; chk < NCHUNK; ++chk) {
        const int t0 = chk * CH;

        // ---- stage x window for this chunk: x[4*t0-3 .. 4*t0+130] ----
        for (int i = lane; i < 134; i += 64) {
            int g = 4 * t0 - 3 + i;
            xs_c[i] = ((unsigned)g < (unsigned)LSIG) ? xg[(size_t)s * LSIG + g] : 0.f;
        }
        __syncthreads();

        // ---- phase A: pooled1 window [2*t0-1, 2*t0+2*CH+1), 66 x 16 ----
        #pragma unroll 1
        for (int it = 0; it < 17; ++it) {
            int idx = it * 64 + lane;
            if (idx < (2 * CH + 2) * 16) {
                int pl  = idx >> 4;
                int p1g = 2 * t0 - 1 + pl;
                // conv1 window for pooled pos p1g sits at xs_c[2*pl .. 2*pl+3]
                float a0 = fmaf(xs_c[2 * pl + 2], w12,
                           fmaf(xs_c[2 * pl + 1], w11,
                           fmaf(xs_c[2 * pl + 0], w10, b1v)));
                float a1 = fmaf(xs_c[2 * pl + 3], w12,
                           fmaf(xs_c[2 * pl + 2], w11,
                           fmaf(xs_c[2 * pl + 1], w10, b1v)));
                float v = fmaxf(fmaxf(a0, a1), 0.f);
                v = ((unsigned)p1g < (unsigned)(LSIG / 2)) ? v : 0.f;
                p1buf[pl][idx & 15] = v;
            }
        }
        __syncthreads();

        // ---- phase B: conv2 + relu + maxpool2 -> seqb[CH][32] ----
        #pragma unroll 1
        for (int it = 0; it < (CH * 32) / 64; ++it) {  // 16 iters
            int tl = it * 2 + tl_b;
            float acc0 = b2v, acc1 = b2v;
            #pragma unroll
            for (int r = 0; r < 4; ++r) {
                float row[16];
                const float4* rp = (const float4*)(&p1buf[2 * tl + r][0]);
                #pragma unroll
                for (int u = 0; u < 4; ++u) ((float4*)row)[u] = rp[u];
                if (r < 3) {
                    #pragma unroll
                    for (int cc = 0; cc < 16; ++cc)
                        acc0 = fmaf(row[cc], w2r[cc * 3 + r], acc0);
                }
                if (r >= 1) {
                    #pragma unroll
                    for (int cc = 0; cc < 16; ++cc)
                        acc1 = fmaf(row[cc], w2r[cc * 3 + (r - 1)], acc1);
                }
            }
            seqb[tl][co] = fmaxf(fmaxf(acc0, acc1), 0.f);
        }
        __syncthreads();

        // ---- phase C: LSTM over CH steps ----
        #pragma unroll 1
        for (int tl = 0; tl < CH; ++tl) {
            float g0 = bs0, g1 = bs1;
            #pragma unroll
            for (int kk = 0; kk < 8; ++kk) {
                const float4 xv = *(const float4*)(&seqb[tl][kk * 4]);
                const float4 hv = *(const float4*)(&hbuf[kk * 4]);
                g0 = fmaf(xv.x, wi0[4 * kk + 0], g0);
                g0 = fmaf(xv.y, wi0[4 * kk + 1], g0);
                g0 = fmaf(xv.z, wi0[4 * kk + 2], g0);
                g0 = fmaf(xv.w, wi0[4 * kk + 3], g0);
                g1 = fmaf(xv.x, wi1[4 * kk + 0], g1);
                g1 = fmaf(xv.y, wi1[4 * kk + 1], g1);
                g1 = fmaf(xv.z, wi1[4 * kk + 2], g1);
                g1 = fmaf(xv.w, wi1[4 * kk + 3], g1);
                g0 = fmaf(hv.x, wh0[4 * kk + 0], g0);
                g0 = fmaf(hv.y, wh0[4 * kk + 1], g0);
                g0 = fmaf(hv.z, wh0[4 * kk + 2], g0);
                g0 = fmaf(hv.w, wh0[4 * kk + 3], g0);
                g1 = fmaf(hv.x, wh1[4 * kk + 0], g1);
                g1 = fmaf(hv.y, wh1[4 * kk + 1], g1);
                g1 = fmaf(hv.z, wh1[4 * kk + 2], g1);
                g1 = fmaf(hv.w, wh1[4 * kk + 3], g1);
            }
            // lane m<32 holds i_m,g_m ; lane 32+m holds f_m,o_m
            float a0 = sigf(g0);                         // sig(i) or sig(f)
            // a1: tanh(g1) for lanes<32, sigmoid(g1) for lanes>=32 — one exp,
            // one divide. tanh = (e^{2x}-1)/(e^{2x}+1); sig = 1/(e^{-x}+1).
            float earg = (lane < 32) ? 2.f * g1 : -g1;
            float e1 = __expf(fminf(earg, 80.f));        // clamp: avoid inf/inf
            float num = (lane < 32) ? e1 - 1.f : 1.f;
            float a1 = __fdividef(num, e1 + 1.f);
            float fa = __shfl_xor(a0, 32);               // sig(f) for lanes<32
            float oa = __shfl_xor(a1, 32);               // sig(o) for lanes<32
            if (lane < 32) {
                c_state = fmaf(fa, c_state, a0 * a1);
                hbuf[lane] = oa * tanhfast(c_state);
            }
            __syncthreads();
        }
    }

    if (lane < 32)
        feats[((size_t)br * BATCH + s) * 32 + lane] = hbuf[lane];
}

// ---------------- tail: bottleneck + 8-qubit statevector + classifier -------

__device__ __forceinline__ void apply1q(float2* psi, int lane, int q,
                                        float2 g00, float2 g01,
                                        float2 g10, float2 g11)
{
    const int shift = 7 - q;
    const int right = 1 << shift;
    #pragma unroll
    for (int pp = 0; pp < 2; ++pp) {
        int p  = lane + 64 * pp;
        int l  = p >> shift;
        int r  = p & (right - 1);
        int i0 = (l << (shift + 1)) + r;
        int i1 = i0 + right;
        float2 a = psi[i0], b = psi[i1];
        float2 n0 = make_float2(g00.x * a.x - g00.y * a.y + g01.x * b.x - g01.y * b.y,
                                g00.x * a.y + g00.y * a.x + g01.x * b.y + g01.y * b.x);
        float2 n1 = make_float2(g10.x * a.x - g10.y * a.y + g11.x * b.x - g11.y * b.y,
                                g10.x * a.y + g10.y * a.x + g11.x * b.y + g11.y * b.x);
        psi[i0] = n0;
        psi[i1] = n1;
    }
    __syncthreads();
}

__global__ __launch_bounds__(64) void tail_kernel(
    const float* __restrict__ feats, const float* __restrict__ bw,
    const float* __restrict__ bb, const float* __restrict__ qw,
    const float* __restrict__ cw, const float* __restrict__ cb,
    float* __restrict__ out)
{
    const int s    = blockIdx.x;
    const int lane = threadIdx.x;

    __shared__ float comb[128];
    __shared__ float2 psi[256];
    __shared__ float ang[8];

    // combined[br*32+k] = feats[br][s][k]
    comb[lane]      = feats[(size_t)(lane >> 5) * (BATCH * 32) + (size_t)s * 32 + (lane & 31)];
    comb[lane + 64] = feats[(size_t)((lane + 64) >> 5) * (BATCH * 32) + (size_t)s * 32 + (lane & 31)];
    __syncthreads();

    // bottleneck: compressed[q] = tanh(comb . bott_w[q] + bott_b[q]); 8 lanes/q
    {
        int q = lane >> 3, k0 = lane & 7;
        float p = 0.f;
        #pragma unroll
        for (int i = 0; i < 16; ++i) {
            int k = k0 + 8 * i;
            p = fmaf(comb[k], bw[q * 128 + k], p);
        }
        p += __shfl_xor(p, 4);
        p += __shfl_xor(p, 2);
        p += __shfl_xor(p, 1);
        if (k0 == 0) ang[q] = tanhf(p + bb[q]);
    }
    // init |0...0>
    #pragma unroll
    for (int r = 0; r < 4; ++r) {
        int idx = lane + 64 * r;
        psi[idx] = make_float2(idx == 0 ? 1.f : 0.f, 0.f);
    }
    __syncthreads();

    const float PI_F = 3.14159265358979323846f;

    // RX embedding (per-sample angles)
    for (int q = 0; q < 8; ++q) {
        float half = ang[q] * PI_F * 0.5f;
        float cv = cosf(half), sv = sinf(half);
        apply1q(psi, lane, q,
                make_float2(cv, 0.f), make_float2(0.f, -sv),
                make_float2(0.f, -sv), make_float2(cv, 0.f));
    }

    // entangling layers: Rot = RZ(omega) RY(theta) RZ(phi), then CNOT ring
    for (int l = 0; l < 3; ++l) {
        for (int q = 0; q < 8; ++q) {
            float phi = qw[(l * 8 + q) * 3 + 0];
            float th  = qw[(l * 8 + q) * 3 + 1];
            float om  = qw[(l * 8 + q) * 3 + 2];
            float ct = cosf(0.5f * th), st = sinf(0.5f * th);
            float A = 0.5f * (phi + om), D = 0.5f * (phi - om);
            float cA = cosf(A), sA = sinf(A), cD = cosf(D), sD = sinf(D);
            apply1q(psi, lane, q,
                    make_float2(ct * cA, -ct * sA), make_float2(-st * cD, -st * sD),
                    make_float2(st * cD, -st * sD), make_float2(ct * cA,  ct * sA));
        }
        int stride = l + 1;
        for (int q = 0; q + stride < 8; ++q) {
            int cbit = 1 << (7 - q);
            int tbit = 1 << (7 - (q + stride));
            #pragma unroll
            for (int r = 0; r < 4; ++r) {
                int idx = lane + 64 * r;
                if ((idx & cbit) && !(idx & tbit)) {
                    int j = idx | tbit;
                    float2 tmp = psi[idx];
                    psi[idx] = psi[j];
                    psi[j] = tmp;
                }
            }
            __syncthreads();
        }
    }

    // <Z_i> then classifier
    float z[8];
    #pragma unroll
    for (int q = 0; q < 8; ++q) z[q] = 0.f;
    #pragma unroll
    for (int r = 0; r < 4; ++r) {
        int idx = lane + 64 * r;
        float2 a = psi[idx];
        float pr = a.x * a.x + a.y * a.y;
        #pragma unroll
        for (int q = 0; q < 8; ++q)
            z[q] += (idx & (1 << (7 - q))) ? -pr : pr;
    }
    #pragma unroll
    for (int q = 0; q < 8; ++q) {
        #pragma unroll
        for (int off = 32; off; off >>= 1) z[q] += __shfl_xor(z[q], off);
    }
    if (lane == 0) {
        #pragma unroll
        for (int c = 0; c < 3; ++c) {
            float acc = cb[c];
            #pragma unroll
            for (int q = 0; q < 8; ++q) acc = fmaf(z[q], cw[c * 8 + q], acc);
            out[s * 3 + c] = acc;
        }
    }
}

extern "C" void kernel_launch(void* const* d_in, const int* in_sizes, int n_in,
                              void* d_out, int out_size, void* d_ws, size_t ws_size,
                              hipStream_t stream)
{
    (void)in_sizes; (void)n_in; (void)out_size; (void)ws_size;
    const float* x0  = (const float*)d_in[0];
    const float* x1  = (const float*)d_in[1];
    const float* x2  = (const float*)d_in[2];
    const float* x3  = (const float*)d_in[3];
    const float* c1w = (const float*)d_in[4];
    const float* c1b = (const float*)d_in[5];
    const float* c2w = (const float*)d_in[6];
    const float* c2b = (const float*)d_in[7];
    const float* wih = (const float*)d_in[8];
    const float* whh = (const float*)d_in[9];
    const float* bih = (const float*)d_in[10];
    const float* bhh = (const float*)d_in[11];
    const float* bw  = (const float*)d_in[12];
    const float* bb  = (const float*)d_in[13];
    const float* qw  = (const float*)d_in[14];
    const float* cw  = (const float*)d_in[15];
    const float* cb  = (const float*)d_in[16];

    float* feats = (float*)d_ws;  // [4][BATCH][32] f32 = 1 MB

    branch_kernel<<<dim3(BATCH, 4), 64, 0, stream>>>(
        x0, x1, x2, x3, c1w, c1b, c2w, c2b, wih, whh, bih, bhh, feats);
    tail_kernel<<<BATCH, 64, 0, stream>>>(
        feats, bw, bb, qw, cw, cb, (float*)d_out);
}

// Round 4
// 2741.721 us; speedup vs baseline: 1.2029x; 1.2029x over previous
//
#include <hip/hip_runtime.h>
#include <hip/hip_bf16.h>

#define BATCH 2048
#define LSIG 2048
#define TSTEPS 512
#define CH 32            // LSTM steps per chunk
#define NCHUNK (TSTEPS / CH)

typedef float v2f __attribute__((ext_vector_type(2)));
typedef float v4f __attribute__((ext_vector_type(4)));

__device__ __forceinline__ void pk_fma(v2f& d, v2f a, v2f b) {
    // d.x += a.x*b.x; d.y += a.y*b.y  (VOP3P packed f32 FMA)
    asm("v_pk_fma_f32 %0, %1, %2, %0" : "+v"(d) : "v"(a), "v"(b));
}

__device__ __forceinline__ float sigf(float x) {
    return __fdividef(1.f, 1.f + __expf(-x));
}
__device__ __forceinline__ float tanhfast(float x) {
    return 1.f - __fdividef(2.f, __expf(2.f * x) + 1.f);
}

// 128 threads (2 waves) per (sample, branch).
// Phase A: conv1(1->16,k3,p1)+relu+pool2 (scalar, small).
// Phase B: conv2(16->32,k3,p1)+relu+pool2 — lane pair (co, half) owns 8 input
//          channels (24 weight regs), shfl_xor(1) combine, pk_fma packed.
// Phase C: LSTM — one gate row per lane across 2 waves (64 weight regs),
//          wave0 = i,f rows; wave1 = g,o rows; LDS gbuf + 2 barriers/step.
// Conv weights are reloaded per chunk via asm-opaqued pointers so they are
// dead during phase C -> peak VGPR ~115 -> 4 waves/SIMD (round-3 lesson:
// VGPR HW granularity is pow2; 168 regs = same occupancy as 256).
__global__ __launch_bounds__(128, 4) void branch_kernel(
    const float* __restrict__ x0, const float* __restrict__ x1,
    const float* __restrict__ x2, const float* __restrict__ x3,
    const float* __restrict__ c1w, const float* __restrict__ c1b,
    const float* __restrict__ c2w, const float* __restrict__ c2b,
    const float* __restrict__ wih, const float* __restrict__ whh,
    const float* __restrict__ bih, const float* __restrict__ bhh,
    float* __restrict__ feats)
{
    const int s    = blockIdx.x;
    const int br   = blockIdx.y;
    const int tid  = threadIdx.x;
    const int wave = tid >> 6;
    const int lane = tid & 63;
    const float* xg = (br == 0) ? x0 : (br == 1) ? x1 : (br == 2) ? x2 : x3;

    __shared__ float xs_c[136];      // per-chunk x window (zero-padded)
    __shared__ float p1buf[66][16];  // pooled1 window for one chunk
    __shared__ float seqb[CH][32];   // LSTM inputs for one chunk
    __shared__ float hbuf[32];       // hidden state broadcast
    __shared__ float gbuf[64];       // wave1 -> wave0 gate transfer

    const int ci1 = tid & 15;            // conv1 out-channel
    const int co  = (tid >> 1) & 31;     // conv2 out-channel
    const int hf  = tid & 1;             // conv2 input-channel half
    const int cc0 = hf * 8;

    // ---- LSTM weights: one gate row per lane (resident) ----
    const int row = wave * 64 + lane;    // rows: 0..63 = i,f ; 64..127 = g,o
    v2f wi2[16], wh2[16];
    {
        const v2f* pwi = (const v2f*)(wih + (size_t)(br * 128 + row) * 32);
        const v2f* pwh = (const v2f*)(whh + (size_t)(br * 128 + row) * 32);
        #pragma unroll
        for (int i = 0; i < 16; ++i) { wi2[i] = pwi[i]; wh2[i] = pwh[i]; }
    }
    const float bsv = bih[br * 128 + row] + bhh[br * 128 + row];

    if (tid < 32) hbuf[tid] = 0.f;
    float c_state = 0.f;
    __syncthreads();

    for (int chk = 0; chk < NCHUNK; ++chk) {
        const int t0 = chk * CH;

        // ---- stage x window: x[4*t0-3 .. 4*t0+130] ----
        for (int i = tid; i < 134; i += 128) {
            int g = 4 * t0 - 3 + i;
            xs_c[i] = ((unsigned)g < (unsigned)LSIG) ? xg[(size_t)s * LSIG + g] : 0.f;
        }

        // ---- conv weights: reload per chunk via opaque pointers (keeps them
        //      dead during phase C; asm volatile blocks LICM hoisting) ----
        const float* pc1 = c1w + br * 48 + ci1 * 3;
        asm volatile("" : "+v"(pc1));
        const float* pb1 = c1b + br * 16 + ci1;
        asm volatile("" : "+v"(pb1));
        const float w10 = pc1[0], w11 = pc1[1], w12 = pc1[2];
        const float b1v = pb1[0];

        const float* pc2 = c2w + br * 1536 + co * 48 + cc0 * 3;
        asm volatile("" : "+v"(pc2));
        const float* pb2 = c2b + br * 32 + co;
        asm volatile("" : "+v"(pb2));
        float wt[24];
        #pragma unroll
        for (int i = 0; i < 6; ++i) ((float4*)wt)[i] = ((const float4*)pc2)[i];
        v2f w2p[3][4];
        #pragma unroll
        for (int r = 0; r < 3; ++r)
            #pragma unroll
            for (int p = 0; p < 4; ++p)
                w2p[r][p] = (v2f){ wt[(2 * p) * 3 + r], wt[(2 * p + 1) * 3 + r] };
        const float b2v = pb2[0];
        __syncthreads();

        // ---- phase A: 66 x 16 pooled1 window ----
        #pragma unroll 1
        for (int it = 0; it < 9; ++it) {
            int idx = it * 128 + tid;
            if (idx < 66 * 16) {
                int pl = idx >> 4;
                float xa = xs_c[2 * pl + 0], xb = xs_c[2 * pl + 1];
                float xc = xs_c[2 * pl + 2], xd = xs_c[2 * pl + 3];
                float a0 = fmaf(xc, w12, fmaf(xb, w11, fmaf(xa, w10, b1v)));
                float a1 = fmaf(xd, w12, fmaf(xc, w11, fmaf(xb, w10, b1v)));
                float v = fmaxf(fmaxf(a0, a1), 0.f);
                int p1g = 2 * t0 - 1 + pl;
                v = ((unsigned)p1g < (unsigned)(LSIG / 2)) ? v : 0.f;
                p1buf[pl][idx & 15] = v;
            }
        }
        __syncthreads();

        // ---- phase B: conv2 + relu + pool2 -> seqb ----
        #pragma unroll 1
        for (int it = 0; it < 16; ++it) {
            int tl = it * 2 + wave;
            const float* pb = &p1buf[2 * tl][cc0];
            v2f rw0[4], rw1[4], rw2[4], rw3[4];
            #pragma unroll
            for (int p = 0; p < 4; ++p) {
                rw0[p] = *(const v2f*)(pb + 0 * 16 + 2 * p);
                rw1[p] = *(const v2f*)(pb + 1 * 16 + 2 * p);
                rw2[p] = *(const v2f*)(pb + 2 * 16 + 2 * p);
                rw3[p] = *(const v2f*)(pb + 3 * 16 + 2 * p);
            }
            v2f accA = {0.f, 0.f}, accB = {0.f, 0.f};
            #pragma unroll
            for (int p = 0; p < 4; ++p) {
                pk_fma(accA, rw0[p], w2p[0][p]);
                pk_fma(accB, rw1[p], w2p[0][p]);
                pk_fma(accA, rw1[p], w2p[1][p]);
                pk_fma(accB, rw2[p], w2p[1][p]);
                pk_fma(accA, rw2[p], w2p[2][p]);
                pk_fma(accB, rw3[p], w2p[2][p]);
            }
            float sA = accA.x + accA.y;
            float sB = accB.x + accB.y;
            sA += __shfl_xor(sA, 1);
            sB += __shfl_xor(sB, 1);
            if (hf == 0)
                seqb[tl][co] = fmaxf(fmaxf(sA, sB) + b2v, 0.f);
        }
        __syncthreads();

        // ---- phase C: LSTM, one gate row per lane ----
        #pragma unroll 1
        for (int tl = 0; tl < CH; ++tl) {
            const float* sr = &seqb[tl][0];
            v2f a0 = {0.f, 0.f}, a1 = {0.f, 0.f}, a2 = {0.f, 0.f}, a3 = {0.f, 0.f};
            #pragma unroll
            for (int j = 0; j < 8; ++j) {
                v2f xv = *(const v2f*)(sr + 2 * j);
                v2f xw = *(const v2f*)(sr + 2 * j + 16);
                pk_fma(a0, xv, wi2[j]);
                pk_fma(a1, xw, wi2[j + 8]);
                v2f hv = *(const v2f*)(hbuf + 2 * j);
                v2f hw = *(const v2f*)(hbuf + 2 * j + 16);
                pk_fma(a2, hv, wh2[j]);
                pk_fma(a3, hw, wh2[j + 8]);
            }
            v2f at = a0 + a1;
            v2f bt = a2 + a3;
            at = at + bt;
            float gate = bsv + at.x + at.y;

            float si = 0.f;
            if (wave == 0) {
                si = sigf(gate);                 // sig(i) lanes<32, sig(f) lanes>=32
            } else {
                // tanh(g) lanes<32, sig(o) lanes>=32 — shared exp
                float earg = (lane < 32) ? 2.f * gate : -gate;
                float e1 = __expf(fminf(earg, 80.f));
                float num = (lane < 32) ? e1 - 1.f : 1.f;
                gbuf[lane] = __fdividef(num, e1 + 1.f);
            }
            __syncthreads();
            if (wave == 0) {
                float fa = __shfl_xor(si, 32);   // sig(f_m) for lanes<32
                if (lane < 32) {
                    float tg = gbuf[lane];        // tanh(g_m)
                    float og = gbuf[lane + 32];   // sig(o_m)
                    c_state = fmaf(fa, c_state, si * tg);
                    hbuf[lane] = og * tanhfast(c_state);
                }
            }
            __syncthreads();
        }
    }

    if (tid < 32)
        feats[((size_t)br * BATCH + s) * 32 + tid] = hbuf[tid];
}

// ---------------- tail: bottleneck + 8-qubit statevector + classifier -------

__device__ __forceinline__ void apply1q(float2* psi, int lane, int q,
                                        float2 g00, float2 g01,
                                        float2 g10, float2 g11)
{
    const int shift = 7 - q;
    const int right = 1 << shift;
    #pragma unroll
    for (int pp = 0; pp < 2; ++pp) {
        int p  = lane + 64 * pp;
        int l  = p >> shift;
        int r  = p & (right - 1);
        int i0 = (l << (shift + 1)) + r;
        int i1 = i0 + right;
        float2 a = psi[i0], b = psi[i1];
        float2 n0 = make_float2(g00.x * a.x - g00.y * a.y + g01.x * b.x - g01.y * b.y,
                                g00.x * a.y + g00.y * a.x + g01.x * b.y + g01.y * b.x);
        float2 n1 = make_float2(g10.x * a.x - g10.y * a.y + g11.x * b.x - g11.y * b.y,
                                g10.x * a.y + g10.y * a.x + g11.x * b.y + g11.y * b.x);
        psi[i0] = n0;
        psi[i1] = n1;
    }
    __syncthreads();
}

__global__ __launch_bounds__(64) void tail_kernel(
    const float* __restrict__ feats, const float* __restrict__ bw,
    const float* __restrict__ bb, const float* __restrict__ qw,
    const float* __restrict__ cw, const float* __restrict__ cb,
    float* __restrict__ out)
{
    const int s    = blockIdx.x;
    const int lane = threadIdx.x;

    __shared__ float comb[128];
    __shared__ float2 psi[256];
    __shared__ float ang[8];

    comb[lane]      = feats[(size_t)(lane >> 5) * (BATCH * 32) + (size_t)s * 32 + (lane & 31)];
    comb[lane + 64] = feats[(size_t)((lane + 64) >> 5) * (BATCH * 32) + (size_t)s * 32 + (lane & 31)];
    __syncthreads();

    {
        int q = lane >> 3, k0 = lane & 7;
        float p = 0.f;
        #pragma unroll
        for (int i = 0; i < 16; ++i) {
            int k = k0 + 8 * i;
            p = fmaf(comb[k], bw[q * 128 + k], p);
        }
        p += __shfl_xor(p, 4);
        p += __shfl_xor(p, 2);
        p += __shfl_xor(p, 1);
        if (k0 == 0) ang[q] = tanhf(p + bb[q]);
    }
    #pragma unroll
    for (int r = 0; r < 4; ++r) {
        int idx = lane + 64 * r;
        psi[idx] = make_float2(idx == 0 ? 1.f : 0.f, 0.f);
    }
    __syncthreads();

    const float PI_F = 3.14159265358979323846f;

    for (int q = 0; q < 8; ++q) {
        float half = ang[q] * PI_F * 0.5f;
        float cv = cosf(half), sv = sinf(half);
        apply1q(psi, lane, q,
                make_float2(cv, 0.f), make_float2(0.f, -sv),
                make_float2(0.f, -sv), make_float2(cv, 0.f));
    }

    for (int l = 0; l < 3; ++l) {
        for (int q = 0; q < 8; ++q) {
            float phi = qw[(l * 8 + q) * 3 + 0];
            float th  = qw[(l * 8 + q) * 3 + 1];
            float om  = qw[(l * 8 + q) * 3 + 2];
            float ct = cosf(0.5f * th), st = sinf(0.5f * th);
            float A = 0.5f * (phi + om), D = 0.5f * (phi - om);
            float cA = cosf(A), sA = sinf(A), cD = cosf(D), sD = sinf(D);
            apply1q(psi, lane, q,
                    make_float2(ct * cA, -ct * sA), make_float2(-st * cD, -st * sD),
                    make_float2(st * cD, -st * sD), make_float2(ct * cA,  ct * sA));
        }
        int stride = l + 1;
        for (int q = 0; q + stride < 8; ++q) {
            int cbit = 1 << (7 - q);
            int tbit = 1 << (7 - (q + stride));
            #pragma unroll
            for (int r = 0; r < 4; ++r) {
                int idx = lane + 64 * r;
                if ((idx & cbit) && !(idx & tbit)) {
                    int j = idx | tbit;
                    float2 tmp = psi[idx];
                    psi[idx] = psi[j];
                    psi[j] = tmp;
                }
            }
            __syncthreads();
        }
    }

    float z[8];
    #pragma unroll
    for (int q = 0; q < 8; ++q) z[q] = 0.f;
    #pragma unroll
    for (int r = 0; r < 4; ++r) {
        int idx = lane + 64 * r;
        float2 a = psi[idx];
        float pr = a.x * a.x + a.y * a.y;
        #pragma unroll
        for (int q = 0; q < 8; ++q)
            z[q] += (idx & (1 << (7 - q))) ? -pr : pr;
    }
    #pragma unroll
    for (int q = 0; q < 8; ++q) {
        #pragma unroll
        for (int off = 32; off; off >>= 1) z[q] += __shfl_xor(z[q], off);
    }
    if (lane == 0) {
        #pragma unroll
        for (int c = 0; c < 3; ++c) {
            float acc = cb[c];
            #pragma unroll
            for (int q = 0; q < 8; ++q) acc = fmaf(z[q], cw[c * 8 + q], acc);
            out[s * 3 + c] = acc;
        }
    }
}

extern "C" void kernel_launch(void* const* d_in, const int* in_sizes, int n_in,
                              void* d_out, int out_size, void* d_ws, size_t ws_size,
                              hipStream_t stream)
{
    (void)in_sizes; (void)n_in; (void)out_size; (void)ws_size;
    const float* x0  = (const float*)d_in[0];
    const float* x1  = (const float*)d_in[1];
    const float* x2  = (const float*)d_in[2];
    const float* x3  = (const float*)d_in[3];
    const float* c1w = (const float*)d_in[4];
    const float* c1b = (const float*)d_in[5];
    const float* c2w = (const float*)d_in[6];
    const float* c2b = (const float*)d_in[7];
    const float* wih = (const float*)d_in[8];
    const float* whh = (const float*)d_in[9];
    const float* bih = (const float*)d_in[10];
    const float* bhh = (const float*)d_in[11];
    const float* bw  = (const float*)d_in[12];
    const float* bb  = (const float*)d_in[13];
    const float* qw  = (const float*)d_in[14];
    const float* cw  = (const float*)d_in[15];
    const float* cb  = (const float*)d_in[16];

    float* feats = (float*)d_ws;  // [4][BATCH][32] f32 = 1 MB

    branch_kernel<<<dim3(BATCH, 4), 128, 0, stream>>>(
        x0, x1, x2, x3, c1w, c1b, c2w, c2b, wih, whh, bih, bhh, feats);
    tail_kernel<<<BATCH, 64, 0, stream>>>(
        feats, bw, bb, qw, cw, cb, (float*)d_out);
}